// Round 6
// baseline (452.902 us; speedup 1.0000x reference)
//
#include <hip/hip_runtime.h>
#include <math.h>

#define DD 2048
#define HH 4096
#define NSTEPS 16
#define KK 4
#define TPB 512
#define NBLK 256u

// workspace float offsets
#define OFF_CAT    0        // h[4096], l[2048] (+pad to 6400)
#define OFF_GI_H   6400     // 12288
#define OFF_GH_H   18688    // 12288
#define OFF_GI_L   30976    // 6144
#define OFF_GH_L   37120    // 6144
#define OFF_DIR    43264    // 2048
#define OFF_RES    45312    // 2048 (res0 / generic res)
#define OFF_RESULT 47360    // 2048
#define OFF_SCAL   49408    // [0]cum [1]weight [3]mom [4]active [5]do_reset [6]raw_conv
                            // [8]conv_dot [9]halt_h_dot [10]p0 [11]p1
#define OFF_XCAT   49472    // [q(2048), l(2048)]
#define OFF_RES2   53568    // 2048 (res1)
#define OFF_FLAGS  57344    // 256 blocks x 4-dword stride = 1024 dwords
#define OFF_GEN    58368    // 1 dword

static __device__ __forceinline__ float sigf(float x) { return 1.0f / (1.0f + expf(-x)); }

static __device__ __forceinline__ float wred(float s) {
#pragma unroll
  for (int off = 32; off; off >>= 1) s += __shfl_down(s, off);
  return s;
}

// depth-8 dual-stream float4 row-dot: 16 loads in flight, 4 accumulators.
static __device__ __forceinline__ float dot8(const float4* __restrict__ Wr,
                                             const float4* __restrict__ x,
                                             int n4, int lane) {
  float a0 = 0.f, a1 = 0.f, a2 = 0.f, a3 = 0.f;
  for (int i = lane; i + 448 < n4; i += 512) {
    float4 w0 = Wr[i],       w1 = Wr[i + 64],  w2 = Wr[i + 128], w3 = Wr[i + 192];
    float4 w4 = Wr[i + 256], w5 = Wr[i + 320], w6 = Wr[i + 384], w7 = Wr[i + 448];
    float4 v0 = x[i],        v1 = x[i + 64],   v2 = x[i + 128],  v3 = x[i + 192];
    float4 v4 = x[i + 256],  v5 = x[i + 320],  v6 = x[i + 384],  v7 = x[i + 448];
    a0 = fmaf(w0.x, v0.x, a0); a0 = fmaf(w0.y, v0.y, a0); a0 = fmaf(w0.z, v0.z, a0); a0 = fmaf(w0.w, v0.w, a0);
    a1 = fmaf(w1.x, v1.x, a1); a1 = fmaf(w1.y, v1.y, a1); a1 = fmaf(w1.z, v1.z, a1); a1 = fmaf(w1.w, v1.w, a1);
    a2 = fmaf(w2.x, v2.x, a2); a2 = fmaf(w2.y, v2.y, a2); a2 = fmaf(w2.z, v2.z, a2); a2 = fmaf(w2.w, v2.w, a2);
    a3 = fmaf(w3.x, v3.x, a3); a3 = fmaf(w3.y, v3.y, a3); a3 = fmaf(w3.z, v3.z, a3); a3 = fmaf(w3.w, v3.w, a3);
    a0 = fmaf(w4.x, v4.x, a0); a0 = fmaf(w4.y, v4.y, a0); a0 = fmaf(w4.z, v4.z, a0); a0 = fmaf(w4.w, v4.w, a0);
    a1 = fmaf(w5.x, v5.x, a1); a1 = fmaf(w5.y, v5.y, a1); a1 = fmaf(w5.z, v5.z, a1); a1 = fmaf(w5.w, v5.w, a1);
    a2 = fmaf(w6.x, v6.x, a2); a2 = fmaf(w6.y, v6.y, a2); a2 = fmaf(w6.z, v6.z, a2); a2 = fmaf(w6.w, v6.w, a2);
    a3 = fmaf(w7.x, v7.x, a3); a3 = fmaf(w7.y, v7.y, a3); a3 = fmaf(w7.z, v7.z, a3); a3 = fmaf(w7.w, v7.w, a3);
  }
  return wred((a0 + a1) + (a2 + a3));
}

// Contention-free grid barrier: per-block flag STORES (parallel) + block-0 scan
// + single gen broadcast. Epoch-monotonic; state zeroed per call via memset.
static __device__ __forceinline__ void fbar(unsigned* flags, unsigned* gen,
                                            unsigned nblk, unsigned& lg) {
  const unsigned e = ++lg;
  __syncthreads();
  if (blockIdx.x == 0) {
    __shared__ int nd;
    long spins = 0;
    while (true) {
      if (threadIdx.x == 0) nd = 0;
      __syncthreads();
      for (unsigned b = 1u + threadIdx.x; b < nblk; b += TPB) {
        if (__hip_atomic_load(&flags[b * 4u], __ATOMIC_ACQUIRE,
                              __HIP_MEMORY_SCOPE_AGENT) < e) nd = 1;
      }
      __syncthreads();
      if (!nd) break;
      __builtin_amdgcn_s_sleep(4);
      if (++spins > (1L << 22)) break;   // safety: never hard-hang
    }
    __threadfence();
    if (threadIdx.x == 0)
      __hip_atomic_store(gen, e, __ATOMIC_RELEASE, __HIP_MEMORY_SCOPE_AGENT);
    __syncthreads();
  } else {
    if (threadIdx.x == 0) {
      __threadfence();
      __hip_atomic_store(&flags[blockIdx.x * 4u], e, __ATOMIC_RELEASE,
                         __HIP_MEMORY_SCOPE_AGENT);
      long spins = 0;
      while (__hip_atomic_load(gen, __ATOMIC_ACQUIRE,
                               __HIP_MEMORY_SCOPE_AGENT) < e) {
        __builtin_amdgcn_s_sleep(8);
        if (++spins > (1L << 22)) break;
      }
      __threadfence();
    }
    __syncthreads();
  }
}

#define FBAR fbar(flags, gen, nblk, lg)

__global__ __launch_bounds__(TPB, 1) void k_all(
    const float* __restrict__ query,
    const float* __restrict__ h_wih, const float* __restrict__ h_whh,
    const float* __restrict__ h_bih, const float* __restrict__ h_bhh,
    const float* __restrict__ l_wih, const float* __restrict__ l_whh,
    const float* __restrict__ l_bih, const float* __restrict__ l_bhh,
    const float* __restrict__ dir_w, const float* __restrict__ dir_b,
    const float* __restrict__ conv_w, const float* __restrict__ conv_b,
    const float* __restrict__ out_w, const float* __restrict__ out_b,
    const float* __restrict__ halt_w, const float* __restrict__ halt_b,
    const float* __restrict__ reset_w, const float* __restrict__ reset_b,
    const float* __restrict__ init_w, const float* __restrict__ init_b,
    float* __restrict__ ws, float* __restrict__ out, unsigned nblk) {
  const int tid = threadIdx.x, lane = tid & 63, wib = tid >> 6;
  const int nw = (int)(gridDim.x << 3);            // 8 waves/block
  const int wid = (int)((blockIdx.x << 3) | wib);
  const int gtid = (int)(blockIdx.x * TPB + tid);
  const int gsz = (int)(gridDim.x * TPB);

  float* cat    = ws + OFF_CAT;
  float* gi_h   = ws + OFF_GI_H;
  float* gh_h   = ws + OFF_GH_H;
  float* gi_l   = ws + OFF_GI_L;
  float* gh_l   = ws + OFF_GH_L;
  float* dir    = ws + OFF_DIR;
  float* res    = ws + OFF_RES;
  float* res2   = ws + OFF_RES2;
  float* result = ws + OFF_RESULT;
  float* scal   = ws + OFF_SCAL;
  float* xcat   = ws + OFF_XCAT;
  unsigned* flags = (unsigned*)(ws + OFF_FLAGS);
  unsigned* gen   = (unsigned*)(ws + OFF_GEN);
  volatile float* vs = scal;
  unsigned lg = 0;

  __shared__ float sbuf[4096];                     // h | {l0, l1}
  const float4* sb4  = (const float4*)sbuf;
  const float4* sb4b = (const float4*)(sbuf + DD);

  const float4* q4 = (const float4*)query;
  const float4* d4 = (const float4*)dir;

  // ---- P0: gi_h = h_wih[:, :2048] @ q + bih  (h=0, l=0 at step 0); seed xcat[q]
  for (int r = wid; r < 3 * HH; r += nw) {
    float s = dot8((const float4*)h_wih + (size_t)r * 1024, q4, 512, lane);
    if (lane == 0) gi_h[r] = s + h_bih[r];
  }
  for (int i = gtid; i < DD; i += gsz) xcat[i] = query[i];
  FBAR;

  // ---- P1: per-block redundant h-combine (gh == bhh) -> LDS; dir; conv/halt-h dots
  for (int i = tid; i < HH; i += TPB) {
    float r = sigf(gi_h[i] + h_bhh[i]);
    float z = sigf(gi_h[HH + i] + h_bhh[HH + i]);
    float n = tanhf(gi_h[2 * HH + i] + r * h_bhh[2 * HH + i]);
    float hv = (1.0f - z) * n;
    sbuf[i] = hv;
    if (blockIdx.x == 0) cat[i] = hv;
  }
  __syncthreads();
  for (int r = wid; r < DD; r += nw) {
    float s = dot8((const float4*)dir_w + (size_t)r * 1024, sb4, 1024, lane);
    if (lane == 0) dir[r] = tanhf(s + dir_b[r]);
  }
  if (blockIdx.x == 0 && wib == 0) {
    float s = 0.f;
    for (int i = lane; i < HH; i += 64) s += conv_w[i] * sbuf[i];
    s = wred(s);
    if (lane == 0) scal[8] = s;
  }
  if (blockIdx.x == 0 && wib == 1) {
    float s = 0.f;
    for (int i = lane; i < HH; i += 64) s += halt_w[i] * sbuf[i];
    s = wred(s);
    if (lane == 0) scal[9] = s;
  }
  FBAR;

  // ---- P2: gi_l = l_wih @ dir + bih
  for (int r = wid; r < 3 * DD; r += nw) {
    float s = dot8((const float4*)l_wih + (size_t)r * 512, d4, 512, lane);
    if (lane == 0) gi_l[r] = s + l_bih[r];
  }
  FBAR;

  // ---- P3: redundant l0-combine (gh==l_bhh) -> LDS; pool gh_l||res0; scalars p0
  for (int i = tid; i < DD; i += TPB) {
    float r = sigf(gi_l[i] + l_bhh[i]);
    float z = sigf(gi_l[DD + i] + l_bhh[DD + i]);
    float n = tanhf(gi_l[2 * DD + i] + r * l_bhh[2 * DD + i]);
    float lv = (1.0f - z) * n;
    sbuf[i] = lv;
    if (blockIdx.x == 0) { cat[HH + i] = lv; xcat[DD + i] = lv; }
  }
  __syncthreads();
  for (int t = wid; t < 8192; t += nw) {
    if (t < 6144) {
      float s = dot8((const float4*)l_whh + (size_t)t * 512, sb4, 512, lane);
      if (lane == 0) gh_l[t] = s + l_bhh[t];
    } else {
      int r2 = t - 6144;
      float s = dot8((const float4*)out_w + (size_t)r2 * 512, sb4, 512, lane);
      if (lane == 0) res[r2] = tanhf(s + out_b[r2]);
    }
  }
  if (blockIdx.x == 0 && wib == 7) {
    float s = 0.f;
    for (int i = lane; i < DD; i += 64) s += halt_w[HH + i] * sbuf[i];
    s = wred(s);
    if (lane == 0) {
      float raw = sigf(scal[8] + conv_b[0]);
      scal[6] = raw;
      scal[3] = 0.1f * raw;                 // mom = 0.9*0 + 0.1*raw
      float halt = sigf(scal[9] + s + halt_b[0]);
      float p = fminf(halt, 1.0f);          // cum was 0
      scal[10] = p;                         // p0
      scal[1] = p; scal[0] = p;             // weight, cum
      scal[4] = (p > 0.95f) ? 0.0f : 1.0f;  // active
      scal[5] = 0.0f;
    }
  }
  FBAR;

  // ---- P4: step 1 (h, dir, gi_l unchanged): l1-combine -> LDS; res1; scalars p1
  bool act0 = (vs[4] != 0.0f);
  if (act0) {
    for (int i = tid; i < DD; i += TPB) {
      float r = sigf(gi_l[i] + gh_l[i]);
      float z = sigf(gi_l[DD + i] + gh_l[DD + i]);
      float n = tanhf(gi_l[2 * DD + i] + r * gh_l[2 * DD + i]);
      float lv = (1.0f - z) * n + z * sbuf[i];
      sbuf[DD + i] = lv;
      if (blockIdx.x == 0) { cat[HH + i] = lv; xcat[DD + i] = lv; }
    }
    __syncthreads();
    for (int r = wid; r < DD; r += nw) {
      float s = dot8((const float4*)out_w + (size_t)r * 512, sb4b, 512, lane);
      if (lane == 0) res2[r] = tanhf(s + out_b[r]);
    }
    if (blockIdx.x == 0 && wib == 7) {
      float s = 0.f;
      for (int i = lane; i < DD; i += 64) s += halt_w[HH + i] * sbuf[DD + i];
      s = wred(s);
      if (lane == 0) {
        scal[3] = 0.9f * scal[3] + 0.1f * scal[6];   // raw unchanged (h unchanged)
        float halt = sigf(scal[9] + s + halt_b[0]);
        float cum = scal[0];
        float p = fminf(halt, 1.0f - cum);
        scal[11] = p;                                 // p1
        scal[1] += p; cum += p; scal[0] = cum;
        scal[4] = (cum > 0.95f) ? 0.0f : 1.0f;
      }
    }
  } else if (blockIdx.x == 0 && tid == 0) {
    scal[11] = 0.0f;
  }
  FBAR;

  // ---- P5: common exit, or rare generic steps 2..15
  bool rare = (vs[4] != 0.0f);
  float p0v = vs[10], p1v = vs[11];
  if (!rare) {
    float wgt = fmaxf(vs[1], 1e-8f);
    for (int i = gtid; i < DD; i += gsz)
      out[i] = (p0v * res[i] + p1v * res2[i]) / wgt;
    return;
  }

  for (int i = gtid; i < DD; i += gsz) result[i] = p0v * res[i] + p1v * res2[i];
  FBAR;
  for (int step = 2; step < NSTEPS; ++step) {
    if (vs[4] == 0.0f) break;
    const bool hstep = ((step & 3) == 0);
    if (hstep) {
      for (int r = wid; r < 6 * HH; r += nw) {
        if (r < 3 * HH) {
          float s = dot8((const float4*)h_wih + (size_t)r * 1024,
                         (const float4*)xcat, 1024, lane);
          if (lane == 0) gi_h[r] = s + h_bih[r];
        } else {
          int rr = r - 3 * HH;
          float s = dot8((const float4*)h_whh + (size_t)rr * 1024,
                         (const float4*)cat, 1024, lane);
          if (lane == 0) gh_h[rr] = s + h_bhh[rr];
        }
      }
      FBAR;
      for (int i = gtid; i < HH; i += gsz) {
        float rr = sigf(gi_h[i] + gh_h[i]);
        float z = sigf(gi_h[HH + i] + gh_h[HH + i]);
        float nn = tanhf(gi_h[2 * HH + i] + rr * gh_h[2 * HH + i]);
        cat[i] = (1.0f - z) * nn + z * cat[i];
      }
      FBAR;
      for (int r = wid; r < DD; r += nw) {
        float s = dot8((const float4*)dir_w + (size_t)r * 1024,
                       (const float4*)cat, 1024, lane);
        if (lane == 0) dir[r] = tanhf(s + dir_b[r]);
      }
      FBAR;
    }
    {
      const int tot = hstep ? 12288 : 6144;   // gi_l only when dir changed
      for (int r = wid; r < tot; r += nw) {
        if (r < 6144) {
          float s = dot8((const float4*)l_whh + (size_t)r * 512,
                         (const float4*)(cat + HH), 512, lane);
          if (lane == 0) gh_l[r] = s + l_bhh[r];
        } else {
          int rr = r - 6144;
          float s = dot8((const float4*)l_wih + (size_t)rr * 512,
                         (const float4*)dir, 512, lane);
          if (lane == 0) gi_l[rr] = s + l_bih[rr];
        }
      }
    }
    FBAR;
    for (int i = gtid; i < DD; i += gsz) {
      float rr = sigf(gi_l[i] + gh_l[i]);
      float z = sigf(gi_l[DD + i] + gh_l[DD + i]);
      float nn = tanhf(gi_l[2 * DD + i] + rr * gh_l[2 * DD + i]);
      float lv = (1.0f - z) * nn + z * cat[HH + i];
      cat[HH + i] = lv;
      xcat[DD + i] = lv;
    }
    FBAR;
    for (int r = wid; r < DD; r += nw) {
      float s = dot8((const float4*)out_w + (size_t)r * 512,
                     (const float4*)(cat + HH), 512, lane);
      if (lane == 0) res[r] = tanhf(s + out_b[r]);
    }
    FBAR;
    if (blockIdx.x == 0) {
      __shared__ float red[4];
      __shared__ float s_p;
      float s = 0.f;
      if (wib == 0) {
        if (hstep) {
          for (int i = lane; i < HH; i += 64) s += conv_w[i] * cat[i];
          s = wred(s);
          if (lane == 0) red[0] = s;
        }
      } else if (wib == 1) {
        for (int i = lane; i < HH + DD; i += 64) s += halt_w[i] * cat[i];
        s = wred(s);
        if (lane == 0) red[1] = s;
      } else if (wib == 2) {
        for (int i = lane; i < HH + DD; i += 64) s += reset_w[i] * cat[i];
        s = wred(s);
        if (lane == 0) red[2] = s;
      }
      __syncthreads();
      if (tid == 0) {
        float raw = hstep ? sigf(red[0] + conv_b[0]) : scal[6];
        if (hstep) scal[6] = raw;
        float mom = 0.9f * scal[3] + 0.1f * raw;
        scal[3] = mom;
        float halt = sigf(red[1] + halt_b[0]);
        float cum = scal[0];
        float p = fminf(halt, 1.0f - cum);
        scal[1] += p;
        cum += p;
        scal[0] = cum;
        bool brk = cum > 0.95f;
        float rdot = red[2] + reset_w[HH + DD] * mom + reset_b[0];
        scal[5] = (!brk && (sigf(rdot) > 0.7f) && (step > KK)) ? 1.0f : 0.0f;
        scal[4] = brk ? 0.0f : 1.0f;
        s_p = p;
      }
      __syncthreads();
      float p = s_p;
      for (int i = tid; i < DD; i += TPB) result[i] += p * res[i];
      __threadfence();
    }
    FBAR;
    if (step > KK && vs[5] != 0.0f) {
      for (int r = wid; r < DD; r += nw) {
        float s = dot8((const float4*)init_w + (size_t)r * 1024,
                       (const float4*)cat, 1024, lane);
        if (lane == 0) {
          float lv = tanhf(s + init_b[r]);
          cat[HH + r] = lv;
          xcat[DD + r] = lv;
        }
      }
      FBAR;
    }
  }
  float wgt = fmaxf(vs[1], 1e-8f);
  for (int i = gtid; i < DD; i += gsz) out[i] = result[i] / wgt;
}

extern "C" void kernel_launch(void* const* d_in, const int* in_sizes, int n_in,
                              void* d_out, int out_size, void* d_ws, size_t ws_size,
                              hipStream_t stream) {
  const float* query   = (const float*)d_in[0];
  const float* h_wih   = (const float*)d_in[1];
  const float* h_whh   = (const float*)d_in[2];
  const float* h_bih   = (const float*)d_in[3];
  const float* h_bhh   = (const float*)d_in[4];
  const float* l_wih   = (const float*)d_in[5];
  const float* l_whh   = (const float*)d_in[6];
  const float* l_bih   = (const float*)d_in[7];
  const float* l_bhh   = (const float*)d_in[8];
  const float* dir_w   = (const float*)d_in[9];
  const float* dir_b   = (const float*)d_in[10];
  const float* conv_w  = (const float*)d_in[11];
  const float* conv_b  = (const float*)d_in[12];
  const float* out_w   = (const float*)d_in[13];
  const float* out_b   = (const float*)d_in[14];
  const float* halt_w  = (const float*)d_in[15];
  const float* halt_b  = (const float*)d_in[16];
  const float* reset_w = (const float*)d_in[17];
  const float* reset_b = (const float*)d_in[18];
  const float* init_w  = (const float*)d_in[19];
  const float* init_b  = (const float*)d_in[20];

  float* ws = (float*)d_ws;
  float* out = (float*)d_out;

  // zero flag-array + gen (epoch state) every call — graph-legal
  hipMemsetAsync((char*)d_ws + (size_t)OFF_FLAGS * 4, 0,
                 (OFF_GEN - OFF_FLAGS + 16) * 4, stream);

  k_all<<<NBLK, TPB, 0, stream>>>(query,
                                  h_wih, h_whh, h_bih, h_bhh,
                                  l_wih, l_whh, l_bih, l_bhh,
                                  dir_w, dir_b, conv_w, conv_b,
                                  out_w, out_b, halt_w, halt_b,
                                  reset_w, reset_b, init_w, init_b,
                                  ws, out, NBLK);
}

// Round 7
// 93.385 us; speedup vs baseline: 4.8498x; 4.8498x over previous
//
#include <hip/hip_runtime.h>
#include <math.h>

#define DD 2048
#define HH 4096
#define NSTEPS 16
#define KK 4

// workspace float offsets
#define OFF_CAT    0        // h[4096], l[2048] (+pad to 6400)
#define OFF_GI_H   6400     // 12288
#define OFF_GH_H   18688    // 12288
#define OFF_GI_L   30976    // 6144
#define OFF_GH_L   37120    // 6144
#define OFF_DIR    43264    // 2048
#define OFF_RES    45312    // 2048 (res0 / generic res)
#define OFF_RESULT 47360    // 2048
#define OFF_SCAL   49408    // [0]cum [1]weight [3]mom [4]active [5]do_reset [6]raw_conv
                            // [8]conv_dot [9]halt_h_dot [10]p0 [11]p1
#define OFF_BAR    49440    // 2 x unsigned (rare-path barrier)
#define OFF_XCAT   49472    // [q(2048), l(2048)]
#define OFF_RES2   53568    // 2048 (res1)
#define OFF_L0     55616    // 2048 (l0 kept immutable for E)

static __device__ __forceinline__ float sigf(float x) { return 1.0f / (1.0f + expf(-x)); }

static __device__ __forceinline__ float wred(float s) {
#pragma unroll
  for (int off = 32; off; off >>= 1) s += __shfl_down(s, off);
  return s;
}

// depth-8 dual-stream float4 row-dot: 16 loads in flight, 4 accumulators.
static __device__ __forceinline__ float dot8(const float4* __restrict__ Wr,
                                             const float4* __restrict__ x,
                                             int n4, int lane) {
  float a0 = 0.f, a1 = 0.f, a2 = 0.f, a3 = 0.f;
  for (int i = lane; i + 448 < n4; i += 512) {
    float4 w0 = Wr[i],       w1 = Wr[i + 64],  w2 = Wr[i + 128], w3 = Wr[i + 192];
    float4 w4 = Wr[i + 256], w5 = Wr[i + 320], w6 = Wr[i + 384], w7 = Wr[i + 448];
    float4 v0 = x[i],        v1 = x[i + 64],   v2 = x[i + 128],  v3 = x[i + 192];
    float4 v4 = x[i + 256],  v5 = x[i + 320],  v6 = x[i + 384],  v7 = x[i + 448];
    a0 = fmaf(w0.x, v0.x, a0); a0 = fmaf(w0.y, v0.y, a0); a0 = fmaf(w0.z, v0.z, a0); a0 = fmaf(w0.w, v0.w, a0);
    a1 = fmaf(w1.x, v1.x, a1); a1 = fmaf(w1.y, v1.y, a1); a1 = fmaf(w1.z, v1.z, a1); a1 = fmaf(w1.w, v1.w, a1);
    a2 = fmaf(w2.x, v2.x, a2); a2 = fmaf(w2.y, v2.y, a2); a2 = fmaf(w2.z, v2.z, a2); a2 = fmaf(w2.w, v2.w, a2);
    a3 = fmaf(w3.x, v3.x, a3); a3 = fmaf(w3.y, v3.y, a3); a3 = fmaf(w3.z, v3.z, a3); a3 = fmaf(w3.w, v3.w, a3);
    a0 = fmaf(w4.x, v4.x, a0); a0 = fmaf(w4.y, v4.y, a0); a0 = fmaf(w4.z, v4.z, a0); a0 = fmaf(w4.w, v4.w, a0);
    a1 = fmaf(w5.x, v5.x, a1); a1 = fmaf(w5.y, v5.y, a1); a1 = fmaf(w5.z, v5.z, a1); a1 = fmaf(w5.w, v5.w, a1);
    a2 = fmaf(w6.x, v6.x, a2); a2 = fmaf(w6.y, v6.y, a2); a2 = fmaf(w6.z, v6.z, a2); a2 = fmaf(w6.w, v6.w, a2);
    a3 = fmaf(w7.x, v7.x, a3); a3 = fmaf(w7.y, v7.y, a3); a3 = fmaf(w7.z, v7.z, a3); a3 = fmaf(w7.w, v7.w, a3);
  }
  return wred((a0 + a1) + (a2 + a3));
}

// rare-path-only software grid barrier (round-4 proven); slow but correct.
static __device__ __forceinline__ void gsync(unsigned* bar, unsigned* gen,
                                             unsigned nblk, unsigned& lg) {
  __syncthreads();
  if (threadIdx.x == 0) {
    __threadfence();
    unsigned arrived = __hip_atomic_fetch_add(bar, 1u, __ATOMIC_ACQ_REL,
                                              __HIP_MEMORY_SCOPE_AGENT);
    if (arrived == nblk - 1) {
      __hip_atomic_store(bar, 0u, __ATOMIC_RELAXED, __HIP_MEMORY_SCOPE_AGENT);
      __hip_atomic_fetch_add(gen, 1u, __ATOMIC_ACQ_REL, __HIP_MEMORY_SCOPE_AGENT);
    } else {
      long spins = 0;
      while (__hip_atomic_load(gen, __ATOMIC_ACQUIRE, __HIP_MEMORY_SCOPE_AGENT) == lg) {
        __builtin_amdgcn_s_sleep(2);
        if (++spins > (1L << 24)) break;
      }
    }
    lg++;
    __threadfence();
  }
  __syncthreads();
}
#define GBAR gsync(bar, bar + 1, nblk, lg)

// ---- A: gi_h = h_wih[:, :2048] @ q + bih  (h=0,l=0 at step 0); seed xcat[q]
__global__ __launch_bounds__(256) void kA_gih(
    const float* __restrict__ h_wih, const float* __restrict__ h_bih,
    const float* __restrict__ query, float* __restrict__ gi_h,
    float* __restrict__ xcat) {
  int gt = blockIdx.x * 256 + threadIdx.x;
  if (gt < DD) xcat[gt] = query[gt];
  int row = gt >> 6;
  if (row >= 3 * HH) return;
  int lane = threadIdx.x & 63;
  float s = dot8((const float4*)h_wih + (size_t)row * 1024, (const float4*)query, 512, lane);
  if (lane == 0) gi_h[row] = s + h_bih[row];
}

// ---- B: per-block redundant h-combine (gh==bhh) -> LDS; dir rows; conv/halt-h dots
__global__ __launch_bounds__(512) void kB_hdir(
    const float* __restrict__ gi_h, const float* __restrict__ h_bhh,
    const float* __restrict__ dir_w, const float* __restrict__ dir_b,
    const float* __restrict__ conv_w, const float* __restrict__ halt_w,
    float* __restrict__ cat, float* __restrict__ dir, float* __restrict__ scal) {
  __shared__ float sbuf[HH];
  int tid = threadIdx.x, lane = tid & 63, wib = tid >> 6;
  for (int i = tid; i < HH; i += 512) {
    float r = sigf(gi_h[i] + h_bhh[i]);
    float z = sigf(gi_h[HH + i] + h_bhh[HH + i]);
    float n = tanhf(gi_h[2 * HH + i] + r * h_bhh[2 * HH + i]);
    float hv = (1.0f - z) * n;
    sbuf[i] = hv;
    if (blockIdx.x == 0) cat[i] = hv;
  }
  __syncthreads();
  int w = (int)(blockIdx.x * 8 + wib);
  if (w < DD) {
    float s = dot8((const float4*)dir_w + (size_t)w * 1024, (const float4*)sbuf, 1024, lane);
    if (lane == 0) dir[w] = tanhf(s + dir_b[w]);
  } else if (w == DD) {
    float s = dot8((const float4*)conv_w, (const float4*)sbuf, 1024, lane);
    if (lane == 0) scal[8] = s;
  } else if (w == DD + 1) {
    float s = dot8((const float4*)halt_w, (const float4*)sbuf, 1024, lane);
    if (lane == 0) scal[9] = s;
  }
}

// ---- C: gi_l = l_wih @ dir + bih
__global__ __launch_bounds__(256) void kC_gil(
    const float* __restrict__ l_wih, const float* __restrict__ l_bih,
    const float* __restrict__ dir, float* __restrict__ gi_l) {
  int row = (int)((blockIdx.x * 256 + threadIdx.x) >> 6);
  if (row >= 3 * DD) return;
  int lane = threadIdx.x & 63;
  float s = dot8((const float4*)l_wih + (size_t)row * 512, (const float4*)dir, 512, lane);
  if (lane == 0) gi_l[row] = s + l_bih[row];
}

// ---- D: per-block l0-combine (gh==l_bhh) -> LDS; pool {gh_l || res0}; p0 scalars
__global__ __launch_bounds__(512) void kD_l0(
    const float* __restrict__ gi_l, const float* __restrict__ l_bhh,
    const float* __restrict__ l_whh, const float* __restrict__ out_w,
    const float* __restrict__ out_b, const float* __restrict__ conv_b,
    const float* __restrict__ halt_w, const float* __restrict__ halt_b,
    float* __restrict__ cat, float* __restrict__ xcat, float* __restrict__ l0g,
    float* __restrict__ gh_l, float* __restrict__ res, float* __restrict__ scal) {
  __shared__ float l0s[DD];
  int tid = threadIdx.x, lane = tid & 63, wib = tid >> 6;
  for (int i = tid; i < DD; i += 512) {
    float r = sigf(gi_l[i] + l_bhh[i]);
    float z = sigf(gi_l[DD + i] + l_bhh[DD + i]);
    float n = tanhf(gi_l[2 * DD + i] + r * l_bhh[2 * DD + i]);
    float lv = (1.0f - z) * n;
    l0s[i] = lv;
    if (blockIdx.x == 0) { cat[HH + i] = lv; xcat[DD + i] = lv; l0g[i] = lv; }
  }
  __syncthreads();
  int wid = (int)(blockIdx.x * 8 + wib);          // 4096 waves, 8192 tasks
  for (int t = wid; t < 8192; t += 4096) {
    if (t < 6144) {
      float s = dot8((const float4*)l_whh + (size_t)t * 512, (const float4*)l0s, 512, lane);
      if (lane == 0) gh_l[t] = s + l_bhh[t];
    } else {
      int r2 = t - 6144;
      float s = dot8((const float4*)out_w + (size_t)r2 * 512, (const float4*)l0s, 512, lane);
      if (lane == 0) res[r2] = tanhf(s + out_b[r2]);
    }
  }
  if (blockIdx.x == 0 && wib == 7) {
    float s = 0.f;
    for (int i = lane; i < DD; i += 64) s += halt_w[HH + i] * l0s[i];
    s = wred(s);
    if (lane == 0) {
      float raw = sigf(scal[8] + conv_b[0]);
      scal[6] = raw;
      scal[3] = 0.1f * raw;                 // mom = 0.9*0 + 0.1*raw
      float halt = sigf(scal[9] + s + halt_b[0]);
      float p = fminf(halt, 1.0f);          // cum was 0
      scal[10] = p;                         // p0
      scal[1] = p; scal[0] = p;             // weight, cum
      scal[4] = (p > 0.95f) ? 0.0f : 1.0f;  // active
      scal[5] = 0.0f;
      scal[11] = 0.0f;                      // p1 default (E may overwrite)
    }
  }
}

// ---- E (gated): per-block l1-combine -> LDS; res1 rows; p1 scalars
__global__ __launch_bounds__(256) void kE_l1(
    const float* __restrict__ gi_l, const float* __restrict__ gh_l,
    const float* __restrict__ l0g, const float* __restrict__ out_w,
    const float* __restrict__ out_b, const float* __restrict__ halt_w,
    const float* __restrict__ halt_b, float* __restrict__ cat,
    float* __restrict__ xcat, float* __restrict__ res2,
    float* __restrict__ scal, const float* __restrict__ gate) {
  if (*gate == 0.0f) return;
  __shared__ float l1s[DD];
  int tid = threadIdx.x, lane = tid & 63, wib = tid >> 6;
  for (int i = tid; i < DD; i += 256) {
    float r = sigf(gi_l[i] + gh_l[i]);
    float z = sigf(gi_l[DD + i] + gh_l[DD + i]);
    float n = tanhf(gi_l[2 * DD + i] + r * gh_l[2 * DD + i]);
    float lv = (1.0f - z) * n + z * l0g[i];
    l1s[i] = lv;
    if (blockIdx.x == 0) { cat[HH + i] = lv; xcat[DD + i] = lv; }
  }
  __syncthreads();
  int w = (int)(blockIdx.x * 4 + wib);            // exactly 2048 rows
  if (w < DD) {
    float s = dot8((const float4*)out_w + (size_t)w * 512, (const float4*)l1s, 512, lane);
    if (lane == 0) res2[w] = tanhf(s + out_b[w]);
  }
  if (blockIdx.x == 0 && wib == 3) {
    float s = 0.f;
    for (int i = lane; i < DD; i += 64) s += halt_w[HH + i] * l1s[i];
    s = wred(s);
    if (lane == 0) {
      scal[3] = 0.9f * scal[3] + 0.1f * scal[6];   // raw unchanged (h unchanged)
      float halt = sigf(scal[9] + s + halt_b[0]);
      float cum = scal[0];
      float p = fminf(halt, 1.0f - cum);
      scal[11] = p;                                 // p1
      scal[1] += p; cum += p; scal[0] = cum;
      scal[4] = (cum > 0.95f) ? 0.0f : 1.0f;
    }
  }
}

// ---- F: fast exit writes output; rare path = generic steps 2..15 (round-4 proven)
__global__ __launch_bounds__(256, 2) void kF_rest(
    const float* __restrict__ h_wih, const float* __restrict__ h_whh,
    const float* __restrict__ h_bih, const float* __restrict__ h_bhh,
    const float* __restrict__ l_wih, const float* __restrict__ l_whh,
    const float* __restrict__ l_bih, const float* __restrict__ l_bhh,
    const float* __restrict__ dir_w, const float* __restrict__ dir_b,
    const float* __restrict__ conv_w, const float* __restrict__ conv_b,
    const float* __restrict__ out_w, const float* __restrict__ out_b,
    const float* __restrict__ halt_w, const float* __restrict__ halt_b,
    const float* __restrict__ reset_w, const float* __restrict__ reset_b,
    const float* __restrict__ init_w, const float* __restrict__ init_b,
    float* __restrict__ ws, float* __restrict__ out, unsigned nblk) {
  const int tid = threadIdx.x, lane = tid & 63, wib = tid >> 6;
  const int nw = (int)(gridDim.x << 2);
  const int wid = (int)((blockIdx.x << 2) | wib);
  const int gtid = (int)(blockIdx.x * 256 + tid);
  const int gsz = (int)(gridDim.x * 256);
  float* cat = ws + OFF_CAT;
  float* gi_h = ws + OFF_GI_H;
  float* gh_h = ws + OFF_GH_H;
  float* gi_l = ws + OFF_GI_L;
  float* gh_l = ws + OFF_GH_L;
  float* dir = ws + OFF_DIR;
  float* res = ws + OFF_RES;
  float* res2 = ws + OFF_RES2;
  float* result = ws + OFF_RESULT;
  float* scal = ws + OFF_SCAL;
  float* xcat = ws + OFF_XCAT;
  unsigned* bar = (unsigned*)(ws + OFF_BAR);
  volatile float* vs = scal;
  unsigned lg = 0;

  float p0v = vs[10], p1v = vs[11];
  if (vs[4] == 0.0f) {                       // common case: halted after <=2 steps
    float wgt = fmaxf(vs[1], 1e-8f);
    for (int i = gtid; i < DD; i += gsz) {
      float acc = p0v * res[i];
      if (p1v != 0.0f) acc += p1v * res2[i]; // guard res2 poison when E skipped
      out[i] = acc / wgt;
    }
    return;
  }

  for (int i = gtid; i < DD; i += gsz) {
    float acc = p0v * res[i];
    if (p1v != 0.0f) acc += p1v * res2[i];
    result[i] = acc;
  }
  GBAR;
  for (int step = 2; step < NSTEPS; ++step) {
    if (vs[4] == 0.0f) break;
    const bool hstep = ((step & 3) == 0);
    if (hstep) {
      for (int r = wid; r < 6 * HH; r += nw) {
        if (r < 3 * HH) {
          float s = dot8((const float4*)h_wih + (size_t)r * 1024,
                         (const float4*)xcat, 1024, lane);
          if (lane == 0) gi_h[r] = s + h_bih[r];
        } else {
          int rr = r - 3 * HH;
          float s = dot8((const float4*)h_whh + (size_t)rr * 1024,
                         (const float4*)cat, 1024, lane);
          if (lane == 0) gh_h[rr] = s + h_bhh[rr];
        }
      }
      GBAR;
      for (int i = gtid; i < HH; i += gsz) {
        float rr = sigf(gi_h[i] + gh_h[i]);
        float z = sigf(gi_h[HH + i] + gh_h[HH + i]);
        float nn = tanhf(gi_h[2 * HH + i] + rr * gh_h[2 * HH + i]);
        cat[i] = (1.0f - z) * nn + z * cat[i];
      }
      GBAR;
      for (int r = wid; r < DD; r += nw) {
        float s = dot8((const float4*)dir_w + (size_t)r * 1024,
                       (const float4*)cat, 1024, lane);
        if (lane == 0) dir[r] = tanhf(s + dir_b[r]);
      }
      GBAR;
    }
    {
      const int tot = hstep ? 12288 : 6144;   // gi_l only when dir changed
      for (int r = wid; r < tot; r += nw) {
        if (r < 6144) {
          float s = dot8((const float4*)l_whh + (size_t)r * 512,
                         (const float4*)(cat + HH), 512, lane);
          if (lane == 0) gh_l[r] = s + l_bhh[r];
        } else {
          int rr = r - 6144;
          float s = dot8((const float4*)l_wih + (size_t)rr * 512,
                         (const float4*)dir, 512, lane);
          if (lane == 0) gi_l[rr] = s + l_bih[rr];
        }
      }
    }
    GBAR;
    for (int i = gtid; i < DD; i += gsz) {
      float rr = sigf(gi_l[i] + gh_l[i]);
      float z = sigf(gi_l[DD + i] + gh_l[DD + i]);
      float nn = tanhf(gi_l[2 * DD + i] + rr * gh_l[2 * DD + i]);
      float lv = (1.0f - z) * nn + z * cat[HH + i];
      cat[HH + i] = lv;
      xcat[DD + i] = lv;
    }
    GBAR;
    for (int r = wid; r < DD; r += nw) {
      float s = dot8((const float4*)out_w + (size_t)r * 512,
                     (const float4*)(cat + HH), 512, lane);
      if (lane == 0) res[r] = tanhf(s + out_b[r]);
    }
    GBAR;
    if (blockIdx.x == 0) {
      __shared__ float red[4];
      __shared__ float s_p;
      float s = 0.f;
      if (wib == 0) {
        if (hstep) {
          for (int i = lane; i < HH; i += 64) s += conv_w[i] * cat[i];
          s = wred(s);
          if (lane == 0) red[0] = s;
        }
      } else if (wib == 1) {
        for (int i = lane; i < HH + DD; i += 64) s += halt_w[i] * cat[i];
        s = wred(s);
        if (lane == 0) red[1] = s;
      } else if (wib == 2) {
        for (int i = lane; i < HH + DD; i += 64) s += reset_w[i] * cat[i];
        s = wred(s);
        if (lane == 0) red[2] = s;
      }
      __syncthreads();
      if (tid == 0) {
        float raw = hstep ? sigf(red[0] + conv_b[0]) : scal[6];
        if (hstep) scal[6] = raw;
        float mom = 0.9f * scal[3] + 0.1f * raw;
        scal[3] = mom;
        float halt = sigf(red[1] + halt_b[0]);
        float cum = scal[0];
        float p = fminf(halt, 1.0f - cum);
        scal[1] += p;
        cum += p;
        scal[0] = cum;
        bool brk = cum > 0.95f;
        float rdot = red[2] + reset_w[HH + DD] * mom + reset_b[0];
        scal[5] = (!brk && (sigf(rdot) > 0.7f) && (step > KK)) ? 1.0f : 0.0f;
        scal[4] = brk ? 0.0f : 1.0f;
        s_p = p;
      }
      __syncthreads();
      float p = s_p;
      for (int i = tid; i < DD; i += 256) result[i] += p * res[i];
      __threadfence();
    }
    GBAR;
    if (step > KK && vs[5] != 0.0f) {
      for (int r = wid; r < DD; r += nw) {
        float s = dot8((const float4*)init_w + (size_t)r * 1024,
                       (const float4*)cat, 1024, lane);
        if (lane == 0) {
          float lv = tanhf(s + init_b[r]);
          cat[HH + r] = lv;
          xcat[DD + r] = lv;
        }
      }
      GBAR;
    }
  }
  float wgt = fmaxf(vs[1], 1e-8f);
  for (int i = gtid; i < DD; i += gsz) out[i] = result[i] / wgt;
}

extern "C" void kernel_launch(void* const* d_in, const int* in_sizes, int n_in,
                              void* d_out, int out_size, void* d_ws, size_t ws_size,
                              hipStream_t stream) {
  const float* query   = (const float*)d_in[0];
  const float* h_wih   = (const float*)d_in[1];
  const float* h_whh   = (const float*)d_in[2];
  const float* h_bih   = (const float*)d_in[3];
  const float* h_bhh   = (const float*)d_in[4];
  const float* l_wih   = (const float*)d_in[5];
  const float* l_whh   = (const float*)d_in[6];
  const float* l_bih   = (const float*)d_in[7];
  const float* l_bhh   = (const float*)d_in[8];
  const float* dir_w   = (const float*)d_in[9];
  const float* dir_b   = (const float*)d_in[10];
  const float* conv_w  = (const float*)d_in[11];
  const float* conv_b  = (const float*)d_in[12];
  const float* out_w   = (const float*)d_in[13];
  const float* out_b   = (const float*)d_in[14];
  const float* halt_w  = (const float*)d_in[15];
  const float* halt_b  = (const float*)d_in[16];
  const float* reset_w = (const float*)d_in[17];
  const float* reset_b = (const float*)d_in[18];
  const float* init_w  = (const float*)d_in[19];
  const float* init_b  = (const float*)d_in[20];

  float* ws = (float*)d_ws;
  float* out = (float*)d_out;
  float* cat  = ws + OFF_CAT;
  float* gi_h = ws + OFF_GI_H;
  float* gi_l = ws + OFF_GI_L;
  float* gh_l = ws + OFF_GH_L;
  float* dir  = ws + OFF_DIR;
  float* res  = ws + OFF_RES;
  float* res2 = ws + OFF_RES2;
  float* l0g  = ws + OFF_L0;
  float* scal = ws + OFF_SCAL;
  float* xcat = ws + OFF_XCAT;

  // zero rare-path barrier state (graph-legal)
  hipMemsetAsync((char*)d_ws + (size_t)OFF_BAR * 4, 0, 8, stream);

  // A: gi_h (100 MB)          B: h-combine + dir + dots (34 MB)
  kA_gih<<<3072, 256, 0, stream>>>(h_wih, h_bih, query, gi_h, xcat);
  kB_hdir<<<257, 512, 0, stream>>>(gi_h, h_bhh, dir_w, dir_b, conv_w, halt_w,
                                   cat, dir, scal);
  // C: gi_l (50 MB)
  kC_gil<<<1536, 256, 0, stream>>>(l_wih, l_bih, dir, gi_l);
  // D: l0 + {gh_l || res0} + p0 (67 MB)
  kD_l0<<<512, 512, 0, stream>>>(gi_l, l_bhh, l_whh, out_w, out_b, conv_b,
                                 halt_w, halt_b, cat, xcat, l0g, gh_l, res, scal);
  // E: l1 + res1 + p1 (17 MB, gated)
  kE_l1<<<512, 256, 0, stream>>>(gi_l, gh_l, l0g, out_w, out_b, halt_w, halt_b,
                                 cat, xcat, res2, scal, scal + 4);
  // F: output / rare remainder
  int maxb = 0;
  if (hipOccupancyMaxActiveBlocksPerMultiprocessor(&maxb, kF_rest, 256, 0) != hipSuccess)
    maxb = 1;
  unsigned nblk = (maxb >= 2) ? 512u : 256u;
  kF_rest<<<nblk, 256, 0, stream>>>(h_wih, h_whh, h_bih, h_bhh,
                                    l_wih, l_whh, l_bih, l_bhh,
                                    dir_w, dir_b, conv_w, conv_b,
                                    out_w, out_b, halt_w, halt_b,
                                    reset_w, reset_b, init_w, init_b,
                                    ws, out, nblk);
}

// Round 9
// 67.923 us; speedup vs baseline: 6.6678x; 1.3749x over previous
//
#include <hip/hip_runtime.h>
#include <math.h>

#define DD 2048
#define HH 4096
#define NSTEPS 16
#define KK 4

// workspace float offsets
#define OFF_CAT    0        // h[4096], l[2048] (+pad to 6400)
#define OFF_GI_H   6400     // 12288
#define OFF_GH_H   18688    // 12288
#define OFF_GI_L   30976    // 6144
#define OFF_GH_L   37120    // 6144
#define OFF_DIR    43264    // 2048
#define OFF_RES    45312    // 2048 (res0 / generic res)
#define OFF_RESULT 47360    // 2048
#define OFF_SCAL   49408    // [0]cum [1]weight [3]mom [4]active [5]do_reset [6]raw_conv
                            // [8]conv_dot [9]halt_h_dot [10]p0 [11]p1
#define OFF_BAR    49440    // 2 x unsigned (rare-path barrier)
#define OFF_XCAT   49472    // [q(2048), l(2048)]
#define OFF_RES2   53568    // 2048 (res1)

static __device__ __forceinline__ float sigf(float x) { return 1.0f / (1.0f + expf(-x)); }

static __device__ __forceinline__ float wred(float s) {
#pragma unroll
  for (int off = 32; off; off >>= 1) s += __shfl_down(s, off);
  return s;
}

// depth-8 dual-stream float4 row-dot: 16 loads in flight, 4 accumulators.
static __device__ __forceinline__ float dot8(const float4* __restrict__ Wr,
                                             const float4* __restrict__ x,
                                             int n4, int lane) {
  float a0 = 0.f, a1 = 0.f, a2 = 0.f, a3 = 0.f;
  for (int i = lane; i + 448 < n4; i += 512) {
    float4 w0 = Wr[i],       w1 = Wr[i + 64],  w2 = Wr[i + 128], w3 = Wr[i + 192];
    float4 w4 = Wr[i + 256], w5 = Wr[i + 320], w6 = Wr[i + 384], w7 = Wr[i + 448];
    float4 v0 = x[i],        v1 = x[i + 64],   v2 = x[i + 128],  v3 = x[i + 192];
    float4 v4 = x[i + 256],  v5 = x[i + 320],  v6 = x[i + 384],  v7 = x[i + 448];
    a0 = fmaf(w0.x, v0.x, a0); a0 = fmaf(w0.y, v0.y, a0); a0 = fmaf(w0.z, v0.z, a0); a0 = fmaf(w0.w, v0.w, a0);
    a1 = fmaf(w1.x, v1.x, a1); a1 = fmaf(w1.y, v1.y, a1); a1 = fmaf(w1.z, v1.z, a1); a1 = fmaf(w1.w, v1.w, a1);
    a2 = fmaf(w2.x, v2.x, a2); a2 = fmaf(w2.y, v2.y, a2); a2 = fmaf(w2.z, v2.z, a2); a2 = fmaf(w2.w, v2.w, a2);
    a3 = fmaf(w3.x, v3.x, a3); a3 = fmaf(w3.y, v3.y, a3); a3 = fmaf(w3.z, v3.z, a3); a3 = fmaf(w3.w, v3.w, a3);
    a0 = fmaf(w4.x, v4.x, a0); a0 = fmaf(w4.y, v4.y, a0); a0 = fmaf(w4.z, v4.z, a0); a0 = fmaf(w4.w, v4.w, a0);
    a1 = fmaf(w5.x, v5.x, a1); a1 = fmaf(w5.y, v5.y, a1); a1 = fmaf(w5.z, v5.z, a1); a1 = fmaf(w5.w, v5.w, a1);
    a2 = fmaf(w6.x, v6.x, a2); a2 = fmaf(w6.y, v6.y, a2); a2 = fmaf(w6.z, v6.z, a2); a2 = fmaf(w6.w, v6.w, a2);
    a3 = fmaf(w7.x, v7.x, a3); a3 = fmaf(w7.y, v7.y, a3); a3 = fmaf(w7.z, v7.z, a3); a3 = fmaf(w7.w, v7.w, a3);
  }
  return wred((a0 + a1) + (a2 + a3));
}

// rare-path-only software grid barrier (round-4 proven); slow but correct.
static __device__ __forceinline__ void gsync(unsigned* bar, unsigned* gen,
                                             unsigned nblk, unsigned& lg) {
  __syncthreads();
  if (threadIdx.x == 0) {
    __threadfence();
    unsigned arrived = __hip_atomic_fetch_add(bar, 1u, __ATOMIC_ACQ_REL,
                                              __HIP_MEMORY_SCOPE_AGENT);
    if (arrived == nblk - 1) {
      __hip_atomic_store(bar, 0u, __ATOMIC_RELAXED, __HIP_MEMORY_SCOPE_AGENT);
      __hip_atomic_fetch_add(gen, 1u, __ATOMIC_ACQ_REL, __HIP_MEMORY_SCOPE_AGENT);
    } else {
      long spins = 0;
      while (__hip_atomic_load(gen, __ATOMIC_ACQUIRE, __HIP_MEMORY_SCOPE_AGENT) == lg) {
        __builtin_amdgcn_s_sleep(2);
        if (++spins > (1L << 24)) break;
      }
    }
    lg++;
    __threadfence();
  }
  __syncthreads();
}
#define GBAR gsync(bar, bar + 1, nblk, lg)

// ---- A: gi_h = h_wih[:, :2048] @ q + bih  (h=0,l=0 at step 0); seed xcat[q]
__global__ __launch_bounds__(256) void kA_gih(
    const float* __restrict__ h_wih, const float* __restrict__ h_bih,
    const float* __restrict__ query, float* __restrict__ gi_h,
    float* __restrict__ xcat) {
  int gt = blockIdx.x * 256 + threadIdx.x;
  if (gt < DD) xcat[gt] = query[gt];
  int row = gt >> 6;
  if (row >= 3 * HH) return;
  int lane = threadIdx.x & 63;
  float s = dot8((const float4*)h_wih + (size_t)row * 1024, (const float4*)query, 512, lane);
  if (lane == 0) gi_h[row] = s + h_bih[row];
}

// ---- B1: step-0 h-combine (gh == bhh since h was 0) + barrier init
__global__ __launch_bounds__(256) void s0_hcombine(
    const float* __restrict__ gi, const float* __restrict__ bhh,
    float* __restrict__ cat, unsigned* __restrict__ bar) {
  int i = blockIdx.x * 256 + threadIdx.x;
  if (i < HH) {
    float r = sigf(gi[i] + bhh[i]);
    float z = sigf(gi[HH + i] + bhh[HH + i]);
    float n = tanhf(gi[2 * HH + i] + r * bhh[2 * HH + i]);
    cat[i] = (1.0f - z) * n;
  }
  if (i < 2) bar[i] = 0u;
}

// ---- B2: dir = tanh(dir_w @ h + b); conv dot -> scal[8]; halt-h dot -> scal[9]
__global__ __launch_bounds__(256) void k_dir_conv(
    const float* __restrict__ dir_w, const float* __restrict__ dir_b,
    const float* __restrict__ conv_w, const float* __restrict__ halt_w,
    const float* __restrict__ cat, float* __restrict__ dirv,
    float* __restrict__ scal) {
  int w = (int)((blockIdx.x * 256 + threadIdx.x) >> 6);
  int lane = threadIdx.x & 63;
  if (w < DD) {
    float s = dot8((const float4*)dir_w + (size_t)w * 1024, (const float4*)cat, 1024, lane);
    if (lane == 0) dirv[w] = tanhf(s + dir_b[w]);
  } else if (w == DD) {
    float s = dot8((const float4*)conv_w, (const float4*)cat, 1024, lane);
    if (lane == 0) scal[8] = s;
  } else if (w == DD + 1) {
    float s = dot8((const float4*)halt_w, (const float4*)cat, 1024, lane);
    if (lane == 0) scal[9] = s;
  }
}

// ---- C: gi_l = l_wih @ dir + bih
__global__ __launch_bounds__(256) void kC_gil(
    const float* __restrict__ l_wih, const float* __restrict__ l_bih,
    const float* __restrict__ dir, float* __restrict__ gi_l) {
  int row = (int)((blockIdx.x * 256 + threadIdx.x) >> 6);
  if (row >= 3 * DD) return;
  int lane = threadIdx.x & 63;
  float s = dot8((const float4*)l_wih + (size_t)row * 512, (const float4*)dir, 512, lane);
  if (lane == 0) gi_l[row] = s + l_bih[row];
}

// ---- D1: step-0 l-combine (gh_l == l_bhh since l was 0) + halt-l + p0 scalars
__global__ __launch_bounds__(1024) void s0_B(
    const float* __restrict__ gi_l, const float* __restrict__ l_bhh,
    float* __restrict__ cat, float* __restrict__ xcat,
    const float* __restrict__ conv_b, const float* __restrict__ halt_w,
    const float* __restrict__ halt_b, float* __restrict__ scal) {
  __shared__ float red[16];
  int tid = threadIdx.x, lane = tid & 63, wib = tid >> 6;
  for (int i = tid; i < DD; i += 1024) {
    float r = sigf(gi_l[i] + l_bhh[i]);
    float z = sigf(gi_l[DD + i] + l_bhh[DD + i]);
    float n = tanhf(gi_l[2 * DD + i] + r * l_bhh[2 * DD + i]);
    float lv = (1.0f - z) * n;
    cat[HH + i] = lv;
    xcat[DD + i] = lv;
  }
  __syncthreads();
  float s = 0.f;
  for (int i = tid; i < DD; i += 1024) s += halt_w[HH + i] * cat[HH + i];
  s = wred(s);
  if (lane == 0) red[wib] = s;
  __syncthreads();
  if (tid == 0) {
    float hl = 0.f;
#pragma unroll
    for (int k = 0; k < 16; k++) hl += red[k];
    float raw = sigf(scal[8] + conv_b[0]);
    scal[6] = raw;
    scal[3] = 0.1f * raw;                 // mom = 0.9*0 + 0.1*raw
    float halt = sigf(scal[9] + hl + halt_b[0]);
    float p = fminf(halt, 1.0f);          // cum was 0
    scal[10] = p;                         // p0
    scal[11] = 0.0f;                      // p1 default
    scal[1] = p;                          // weight
    scal[0] = p;                          // cum
    scal[4] = (p > 0.95f) ? 0.0f : 1.0f;  // active
    scal[5] = 0.0f;
  }
}

// ---- D2: task pool {gh_l (6144 rows) || res0 (2048 rows)} — both read l0 only
__global__ __launch_bounds__(256) void kDE_pool(
    const float* __restrict__ l_whh, const float* __restrict__ l_bhh,
    const float* __restrict__ out_w, const float* __restrict__ out_b,
    const float* __restrict__ cat, float* __restrict__ gh_l,
    float* __restrict__ res) {
  int t = (int)((blockIdx.x * 256 + threadIdx.x) >> 6);
  if (t >= 8192) return;
  int lane = threadIdx.x & 63;
  const float4* l04 = (const float4*)(cat + HH);
  if (t < 6144) {
    float s = dot8((const float4*)l_whh + (size_t)t * 512, l04, 512, lane);
    if (lane == 0) gh_l[t] = s + l_bhh[t];
  } else {
    int r = t - 6144;
    float s = dot8((const float4*)out_w + (size_t)r * 512, l04, 512, lane);
    if (lane == 0) res[r] = tanhf(s + out_b[r]);
  }
}

// ---- E1: step-1 l-combine (gi_l reused: dir unchanged) + halt-l + p1 scalars
__global__ __launch_bounds__(1024) void s1_B(
    const float* __restrict__ gi_l, const float* __restrict__ gh_l,
    float* __restrict__ cat, float* __restrict__ xcat,
    const float* __restrict__ halt_b, const float* __restrict__ halt_w,
    float* __restrict__ scal) {
  __shared__ float red[16];
  int tid = threadIdx.x, lane = tid & 63, wib = tid >> 6;
  if (scal[4] == 0.0f) return;            // p1 already 0 from s0_B
  for (int i = tid; i < DD; i += 1024) {
    float r = sigf(gi_l[i] + gh_l[i]);
    float z = sigf(gi_l[DD + i] + gh_l[DD + i]);
    float n = tanhf(gi_l[2 * DD + i] + r * gh_l[2 * DD + i]);
    float lv = (1.0f - z) * n + z * cat[HH + i];
    cat[HH + i] = lv;
    xcat[DD + i] = lv;
  }
  __syncthreads();
  float s = 0.f;
  for (int i = tid; i < DD; i += 1024) s += halt_w[HH + i] * cat[HH + i];
  s = wred(s);
  if (lane == 0) red[wib] = s;
  __syncthreads();
  if (tid == 0) {
    float hl = 0.f;
#pragma unroll
    for (int k = 0; k < 16; k++) hl += red[k];
    scal[3] = 0.9f * scal[3] + 0.1f * scal[6];   // raw unchanged (h unchanged)
    float halt = sigf(scal[9] + hl + halt_b[0]);
    float cum = scal[0];
    float p = fminf(halt, 1.0f - cum);
    scal[11] = p;                                 // p1
    scal[1] += p;
    cum += p;
    scal[0] = cum;
    scal[4] = (cum > 0.95f) ? 0.0f : 1.0f;
  }
}

// ---- E2: res1 = tanh(out_w @ l1 + b) — gated on p1 (NOT active: round-8 bug)
__global__ __launch_bounds__(256) void kE_res1(
    const float* __restrict__ out_w, const float* __restrict__ out_b,
    const float* __restrict__ cat, float* __restrict__ res2,
    const float* __restrict__ p1gate) {
  if (*p1gate == 0.0f) return;            // p1 == 0 <=> res1 contributes nothing
  int row = (int)((blockIdx.x * 256 + threadIdx.x) >> 6);
  if (row >= DD) return;
  int lane = threadIdx.x & 63;
  float s = dot8((const float4*)out_w + (size_t)row * 512,
                 (const float4*)(cat + HH), 512, lane);
  if (lane == 0) res2[row] = tanhf(s + out_b[row]);
}

// ---- F: fast exit writes output; rare path = generic steps 2..15 (proven)
__global__ __launch_bounds__(256, 2) void kF_rest(
    const float* __restrict__ h_wih, const float* __restrict__ h_whh,
    const float* __restrict__ h_bih, const float* __restrict__ h_bhh,
    const float* __restrict__ l_wih, const float* __restrict__ l_whh,
    const float* __restrict__ l_bih, const float* __restrict__ l_bhh,
    const float* __restrict__ dir_w, const float* __restrict__ dir_b,
    const float* __restrict__ conv_w, const float* __restrict__ conv_b,
    const float* __restrict__ out_w, const float* __restrict__ out_b,
    const float* __restrict__ halt_w, const float* __restrict__ halt_b,
    const float* __restrict__ reset_w, const float* __restrict__ reset_b,
    const float* __restrict__ init_w, const float* __restrict__ init_b,
    float* __restrict__ ws, float* __restrict__ out, unsigned nblk) {
  const int tid = threadIdx.x, lane = tid & 63, wib = tid >> 6;
  const int nw = (int)(gridDim.x << 2);
  const int wid = (int)((blockIdx.x << 2) | wib);
  const int gtid = (int)(blockIdx.x * 256 + tid);
  const int gsz = (int)(gridDim.x * 256);
  float* cat = ws + OFF_CAT;
  float* gi_h = ws + OFF_GI_H;
  float* gh_h = ws + OFF_GH_H;
  float* gi_l = ws + OFF_GI_L;
  float* gh_l = ws + OFF_GH_L;
  float* dir = ws + OFF_DIR;
  float* res = ws + OFF_RES;
  float* res2 = ws + OFF_RES2;
  float* result = ws + OFF_RESULT;
  float* scal = ws + OFF_SCAL;
  float* xcat = ws + OFF_XCAT;
  unsigned* bar = (unsigned*)(ws + OFF_BAR);
  volatile float* vs = scal;
  unsigned lg = 0;

  float p0v = vs[10], p1v = vs[11];
  if (vs[4] == 0.0f) {                       // common case: halted after <=2 steps
    float wgt = fmaxf(vs[1], 1e-8f);
    for (int i = gtid; i < DD; i += gsz) {
      float acc = p0v * res[i];
      if (p1v != 0.0f) acc += p1v * res2[i]; // guard res2 poison when E skipped
      out[i] = acc / wgt;
    }
    return;
  }

  for (int i = gtid; i < DD; i += gsz) {
    float acc = p0v * res[i];
    if (p1v != 0.0f) acc += p1v * res2[i];
    result[i] = acc;
  }
  GBAR;
  for (int step = 2; step < NSTEPS; ++step) {
    if (vs[4] == 0.0f) break;
    const bool hstep = ((step & 3) == 0);
    if (hstep) {
      for (int r = wid; r < 6 * HH; r += nw) {
        if (r < 3 * HH) {
          float s = dot8((const float4*)h_wih + (size_t)r * 1024,
                         (const float4*)xcat, 1024, lane);
          if (lane == 0) gi_h[r] = s + h_bih[r];
        } else {
          int rr = r - 3 * HH;
          float s = dot8((const float4*)h_whh + (size_t)rr * 1024,
                         (const float4*)cat, 1024, lane);
          if (lane == 0) gh_h[rr] = s + h_bhh[rr];
        }
      }
      GBAR;
      for (int i = gtid; i < HH; i += gsz) {
        float rr = sigf(gi_h[i] + gh_h[i]);
        float z = sigf(gi_h[HH + i] + gh_h[HH + i]);
        float nn = tanhf(gi_h[2 * HH + i] + rr * gh_h[2 * HH + i]);
        cat[i] = (1.0f - z) * nn + z * cat[i];
      }
      GBAR;
      for (int r = wid; r < DD; r += nw) {
        float s = dot8((const float4*)dir_w + (size_t)r * 1024,
                       (const float4*)cat, 1024, lane);
        if (lane == 0) dir[r] = tanhf(s + dir_b[r]);
      }
      GBAR;
    }
    {
      const int tot = hstep ? 12288 : 6144;   // gi_l only when dir changed
      for (int r = wid; r < tot; r += nw) {
        if (r < 6144) {
          float s = dot8((const float4*)l_whh + (size_t)r * 512,
                         (const float4*)(cat + HH), 512, lane);
          if (lane == 0) gh_l[r] = s + l_bhh[r];
        } else {
          int rr = r - 6144;
          float s = dot8((const float4*)l_wih + (size_t)rr * 512,
                         (const float4*)dir, 512, lane);
          if (lane == 0) gi_l[rr] = s + l_bih[rr];
        }
      }
    }
    GBAR;
    for (int i = gtid; i < DD; i += gsz) {
      float rr = sigf(gi_l[i] + gh_l[i]);
      float z = sigf(gi_l[DD + i] + gh_l[DD + i]);
      float nn = tanhf(gi_l[2 * DD + i] + rr * gh_l[2 * DD + i]);
      float lv = (1.0f - z) * nn + z * cat[HH + i];
      cat[HH + i] = lv;
      xcat[DD + i] = lv;
    }
    GBAR;
    for (int r = wid; r < DD; r += nw) {
      float s = dot8((const float4*)out_w + (size_t)r * 512,
                     (const float4*)(cat + HH), 512, lane);
      if (lane == 0) res[r] = tanhf(s + out_b[r]);
    }
    GBAR;
    if (blockIdx.x == 0) {
      __shared__ float red[4];
      __shared__ float s_p;
      float s = 0.f;
      if (wib == 0) {
        if (hstep) {
          for (int i = lane; i < HH; i += 64) s += conv_w[i] * cat[i];
          s = wred(s);
          if (lane == 0) red[0] = s;
        }
      } else if (wib == 1) {
        for (int i = lane; i < HH + DD; i += 64) s += halt_w[i] * cat[i];
        s = wred(s);
        if (lane == 0) red[1] = s;
      } else if (wib == 2) {
        for (int i = lane; i < HH + DD; i += 64) s += reset_w[i] * cat[i];
        s = wred(s);
        if (lane == 0) red[2] = s;
      }
      __syncthreads();
      if (tid == 0) {
        float raw = hstep ? sigf(red[0] + conv_b[0]) : scal[6];
        if (hstep) scal[6] = raw;
        float mom = 0.9f * scal[3] + 0.1f * raw;
        scal[3] = mom;
        float halt = sigf(red[1] + halt_b[0]);
        float cum = scal[0];
        float p = fminf(halt, 1.0f - cum);
        scal[1] += p;
        cum += p;
        scal[0] = cum;
        bool brk = cum > 0.95f;
        float rdot = red[2] + reset_w[HH + DD] * mom + reset_b[0];
        scal[5] = (!brk && (sigf(rdot) > 0.7f) && (step > KK)) ? 1.0f : 0.0f;
        scal[4] = brk ? 0.0f : 1.0f;
        s_p = p;
      }
      __syncthreads();
      float p = s_p;
      for (int i = tid; i < DD; i += 256) result[i] += p * res[i];
      __threadfence();
    }
    GBAR;
    if (step > KK && vs[5] != 0.0f) {
      for (int r = wid; r < DD; r += nw) {
        float s = dot8((const float4*)init_w + (size_t)r * 1024,
                       (const float4*)cat, 1024, lane);
        if (lane == 0) {
          float lv = tanhf(s + init_b[r]);
          cat[HH + r] = lv;
          xcat[DD + r] = lv;
        }
      }
      GBAR;
    }
  }
  float wgt = fmaxf(vs[1], 1e-8f);
  for (int i = gtid; i < DD; i += gsz) out[i] = result[i] / wgt;
}

extern "C" void kernel_launch(void* const* d_in, const int* in_sizes, int n_in,
                              void* d_out, int out_size, void* d_ws, size_t ws_size,
                              hipStream_t stream) {
  const float* query   = (const float*)d_in[0];
  const float* h_wih   = (const float*)d_in[1];
  const float* h_whh   = (const float*)d_in[2];
  const float* h_bih   = (const float*)d_in[3];
  const float* h_bhh   = (const float*)d_in[4];
  const float* l_wih   = (const float*)d_in[5];
  const float* l_whh   = (const float*)d_in[6];
  const float* l_bih   = (const float*)d_in[7];
  const float* l_bhh   = (const float*)d_in[8];
  const float* dir_w   = (const float*)d_in[9];
  const float* dir_b   = (const float*)d_in[10];
  const float* conv_w  = (const float*)d_in[11];
  const float* conv_b  = (const float*)d_in[12];
  const float* out_w   = (const float*)d_in[13];
  const float* out_b   = (const float*)d_in[14];
  const float* halt_w  = (const float*)d_in[15];
  const float* halt_b  = (const float*)d_in[16];
  const float* reset_w = (const float*)d_in[17];
  const float* reset_b = (const float*)d_in[18];
  const float* init_w  = (const float*)d_in[19];
  const float* init_b  = (const float*)d_in[20];

  float* ws = (float*)d_ws;
  float* out = (float*)d_out;
  float* cat  = ws + OFF_CAT;
  float* gi_h = ws + OFF_GI_H;
  float* gi_l = ws + OFF_GI_L;
  float* gh_l = ws + OFF_GH_L;
  float* dir  = ws + OFF_DIR;
  float* res  = ws + OFF_RES;
  float* res2 = ws + OFF_RES2;
  float* scal = ws + OFF_SCAL;
  float* xcat = ws + OFF_XCAT;
  unsigned* bar = (unsigned*)(ws + OFF_BAR);

  // step 0 specialization (h=0, l=0)
  kA_gih<<<3072, 256, 0, stream>>>(h_wih, h_bih, query, gi_h, xcat);
  s0_hcombine<<<16, 256, 0, stream>>>(gi_h, h_bhh, cat, bar);
  k_dir_conv<<<513, 256, 0, stream>>>(dir_w, dir_b, conv_w, halt_w, cat, dir, scal);
  kC_gil<<<1536, 256, 0, stream>>>(l_wih, l_bih, dir, gi_l);
  s0_B<<<1, 1024, 0, stream>>>(gi_l, l_bhh, cat, xcat, conv_b, halt_w, halt_b, scal);
  // {gh_l || res0} task pool (both depend only on l0)
  kDE_pool<<<2048, 256, 0, stream>>>(l_whh, l_bhh, out_w, out_b, cat, gh_l, res);
  // step 1 (h, dir, gi_l unchanged)
  s1_B<<<1, 1024, 0, stream>>>(gi_l, gh_l, cat, xcat, halt_b, halt_w, scal);
  kE_res1<<<512, 256, 0, stream>>>(out_w, out_b, cat, res2, scal + 11);  // gate on p1
  // output / rare remainder
  int maxb = 0;
  if (hipOccupancyMaxActiveBlocksPerMultiprocessor(&maxb, kF_rest, 256, 0) != hipSuccess)
    maxb = 1;
  unsigned nblk = (maxb >= 2) ? 512u : 256u;
  kF_rest<<<nblk, 256, 0, stream>>>(h_wih, h_whh, h_bih, h_bhh,
                                    l_wih, l_whh, l_bih, l_bhh,
                                    dir_w, dir_b, conv_w, conv_b,
                                    out_w, out_b, halt_w, halt_b,
                                    reset_w, reset_b, init_w, init_b,
                                    ws, out, nblk);
}

// Round 10
// 67.371 us; speedup vs baseline: 6.7226x; 1.0082x over previous
//
#include <hip/hip_runtime.h>
#include <math.h>

#define DD 2048
#define HH 4096
#define NSTEPS 16
#define KK 4

// workspace float offsets
#define OFF_CAT    0        // h[4096], l[2048] (+pad to 6400)
#define OFF_GI_H   6400     // 12288
#define OFF_GH_H   18688    // 12288
#define OFF_GI_L   30976    // 6144
#define OFF_GH_L   37120    // 6144
#define OFF_DIR    43264    // 2048
#define OFF_RES    45312    // 2048 (res0 / generic res)
#define OFF_RESULT 47360    // 2048
#define OFF_SCAL   49408    // [0]cum [1]weight [3]mom [4]active [5]do_reset [6]raw_conv
                            // [8]conv_dot [9]halt_h_dot [10]p0 [11]p1
#define OFF_BAR    49440    // 2 x unsigned (rare-path barrier)
#define OFF_XCAT   49472    // [q(2048), l(2048)]

static __device__ __forceinline__ float sigf(float x) { return 1.0f / (1.0f + expf(-x)); }

static __device__ __forceinline__ float wred(float s) {
#pragma unroll
  for (int off = 32; off; off >>= 1) s += __shfl_down(s, off);
  return s;
}

// depth-8 dual-stream float4 row-dot: 16 loads in flight, 4 accumulators.
static __device__ __forceinline__ float dot8(const float4* __restrict__ Wr,
                                             const float4* __restrict__ x,
                                             int n4, int lane) {
  float a0 = 0.f, a1 = 0.f, a2 = 0.f, a3 = 0.f;
  for (int i = lane; i + 448 < n4; i += 512) {
    float4 w0 = Wr[i],       w1 = Wr[i + 64],  w2 = Wr[i + 128], w3 = Wr[i + 192];
    float4 w4 = Wr[i + 256], w5 = Wr[i + 320], w6 = Wr[i + 384], w7 = Wr[i + 448];
    float4 v0 = x[i],        v1 = x[i + 64],   v2 = x[i + 128],  v3 = x[i + 192];
    float4 v4 = x[i + 256],  v5 = x[i + 320],  v6 = x[i + 384],  v7 = x[i + 448];
    a0 = fmaf(w0.x, v0.x, a0); a0 = fmaf(w0.y, v0.y, a0); a0 = fmaf(w0.z, v0.z, a0); a0 = fmaf(w0.w, v0.w, a0);
    a1 = fmaf(w1.x, v1.x, a1); a1 = fmaf(w1.y, v1.y, a1); a1 = fmaf(w1.z, v1.z, a1); a1 = fmaf(w1.w, v1.w, a1);
    a2 = fmaf(w2.x, v2.x, a2); a2 = fmaf(w2.y, v2.y, a2); a2 = fmaf(w2.z, v2.z, a2); a2 = fmaf(w2.w, v2.w, a2);
    a3 = fmaf(w3.x, v3.x, a3); a3 = fmaf(w3.y, v3.y, a3); a3 = fmaf(w3.z, v3.z, a3); a3 = fmaf(w3.w, v3.w, a3);
    a0 = fmaf(w4.x, v4.x, a0); a0 = fmaf(w4.y, v4.y, a0); a0 = fmaf(w4.z, v4.z, a0); a0 = fmaf(w4.w, v4.w, a0);
    a1 = fmaf(w5.x, v5.x, a1); a1 = fmaf(w5.y, v5.y, a1); a1 = fmaf(w5.z, v5.z, a1); a1 = fmaf(w5.w, v5.w, a1);
    a2 = fmaf(w6.x, v6.x, a2); a2 = fmaf(w6.y, v6.y, a2); a2 = fmaf(w6.z, v6.z, a2); a2 = fmaf(w6.w, v6.w, a2);
    a3 = fmaf(w7.x, v7.x, a3); a3 = fmaf(w7.y, v7.y, a3); a3 = fmaf(w7.z, v7.z, a3); a3 = fmaf(w7.w, v7.w, a3);
  }
  return wred((a0 + a1) + (a2 + a3));
}

// rare-path-only software grid barrier (round-4 proven); slow but correct.
static __device__ __forceinline__ void gsync(unsigned* bar, unsigned* gen,
                                             unsigned nblk, unsigned& lg) {
  __syncthreads();
  if (threadIdx.x == 0) {
    __threadfence();
    unsigned arrived = __hip_atomic_fetch_add(bar, 1u, __ATOMIC_ACQ_REL,
                                              __HIP_MEMORY_SCOPE_AGENT);
    if (arrived == nblk - 1) {
      __hip_atomic_store(bar, 0u, __ATOMIC_RELAXED, __HIP_MEMORY_SCOPE_AGENT);
      __hip_atomic_fetch_add(gen, 1u, __ATOMIC_ACQ_REL, __HIP_MEMORY_SCOPE_AGENT);
    } else {
      long spins = 0;
      while (__hip_atomic_load(gen, __ATOMIC_ACQUIRE, __HIP_MEMORY_SCOPE_AGENT) == lg) {
        __builtin_amdgcn_s_sleep(2);
        if (++spins > (1L << 24)) break;
      }
    }
    lg++;
    __threadfence();
  }
  __syncthreads();
}
#define GBAR gsync(bar, bar + 1, nblk, lg)

// ---- A: gi_h = h_wih[:, :2048] @ q + bih  (h=0,l=0 at step 0); seed xcat[q]
__global__ __launch_bounds__(256) void kA_gih(
    const float* __restrict__ h_wih, const float* __restrict__ h_bih,
    const float* __restrict__ query, float* __restrict__ gi_h,
    float* __restrict__ xcat) {
  int gt = blockIdx.x * 256 + threadIdx.x;
  if (gt < DD) xcat[gt] = query[gt];
  int row = gt >> 6;
  if (row >= 3 * HH) return;
  int lane = threadIdx.x & 63;
  float s = dot8((const float4*)h_wih + (size_t)row * 1024, (const float4*)query, 512, lane);
  if (lane == 0) gi_h[row] = s + h_bih[row];
}

// ---- B1: step-0 h-combine (gh == bhh since h was 0), float4; + barrier init
__global__ __launch_bounds__(256) void s0_hcombine(
    const float* __restrict__ gi, const float* __restrict__ bhh,
    float* __restrict__ cat, unsigned* __restrict__ bar) {
  int c = blockIdx.x * 256 + threadIdx.x;           // 1024 float4 chunks
  if (c < HH / 4) {
    const float4* g4 = (const float4*)gi;
    const float4* b4 = (const float4*)bhh;
    float4 g0 = g4[c], g1 = g4[HH / 4 + c], g2 = g4[HH / 2 + c];
    float4 b0 = b4[c], b1 = b4[HH / 4 + c], b2 = b4[HH / 2 + c];
    float4 o;
    {
      float r = sigf(g0.x + b0.x), z = sigf(g1.x + b1.x);
      o.x = (1.0f - z) * tanhf(g2.x + r * b2.x);
    }
    {
      float r = sigf(g0.y + b0.y), z = sigf(g1.y + b1.y);
      o.y = (1.0f - z) * tanhf(g2.y + r * b2.y);
    }
    {
      float r = sigf(g0.z + b0.z), z = sigf(g1.z + b1.z);
      o.z = (1.0f - z) * tanhf(g2.z + r * b2.z);
    }
    {
      float r = sigf(g0.w + b0.w), z = sigf(g1.w + b1.w);
      o.w = (1.0f - z) * tanhf(g2.w + r * b2.w);
    }
    ((float4*)cat)[c] = o;
  }
  if (c < 2) bar[c] = 0u;
}

// ---- B2: dir = tanh(dir_w @ h + b); conv dot -> scal[8]; halt-h dot -> scal[9]
__global__ __launch_bounds__(256) void k_dir_conv(
    const float* __restrict__ dir_w, const float* __restrict__ dir_b,
    const float* __restrict__ conv_w, const float* __restrict__ halt_w,
    const float* __restrict__ cat, float* __restrict__ dirv,
    float* __restrict__ scal) {
  int w = (int)((blockIdx.x * 256 + threadIdx.x) >> 6);
  int lane = threadIdx.x & 63;
  if (w < DD) {
    float s = dot8((const float4*)dir_w + (size_t)w * 1024, (const float4*)cat, 1024, lane);
    if (lane == 0) dirv[w] = tanhf(s + dir_b[w]);
  } else if (w == DD) {
    float s = dot8((const float4*)conv_w, (const float4*)cat, 1024, lane);
    if (lane == 0) scal[8] = s;
  } else if (w == DD + 1) {
    float s = dot8((const float4*)halt_w, (const float4*)cat, 1024, lane);
    if (lane == 0) scal[9] = s;
  }
}

// ---- C: gi_l = l_wih @ dir + bih
__global__ __launch_bounds__(256) void kC_gil(
    const float* __restrict__ l_wih, const float* __restrict__ l_bih,
    const float* __restrict__ dir, float* __restrict__ gi_l) {
  int row = (int)((blockIdx.x * 256 + threadIdx.x) >> 6);
  if (row >= 3 * DD) return;
  int lane = threadIdx.x & 63;
  float s = dot8((const float4*)l_wih + (size_t)row * 512, (const float4*)dir, 512, lane);
  if (lane == 0) gi_l[row] = s + l_bih[row];
}

// ---- D1: step-0 l-combine (gh_l == l_bhh), float4; + halt-l + p0 scalars
__global__ __launch_bounds__(1024) void s0_B(
    const float* __restrict__ gi_l, const float* __restrict__ l_bhh,
    float* __restrict__ cat, float* __restrict__ xcat,
    const float* __restrict__ conv_b, const float* __restrict__ halt_w,
    const float* __restrict__ halt_b, float* __restrict__ scal) {
  __shared__ float red[16];
  int tid = threadIdx.x, lane = tid & 63, wib = tid >> 6;
  if (tid < DD / 4) {                       // 512 float4 chunks
    const float4* g4 = (const float4*)gi_l;
    const float4* b4 = (const float4*)l_bhh;
    float4 g0 = g4[tid], g1 = g4[DD / 4 + tid], g2 = g4[DD / 2 + tid];
    float4 b0 = b4[tid], b1 = b4[DD / 4 + tid], b2 = b4[DD / 2 + tid];
    float4 o;
    {
      float r = sigf(g0.x + b0.x), z = sigf(g1.x + b1.x);
      o.x = (1.0f - z) * tanhf(g2.x + r * b2.x);
    }
    {
      float r = sigf(g0.y + b0.y), z = sigf(g1.y + b1.y);
      o.y = (1.0f - z) * tanhf(g2.y + r * b2.y);
    }
    {
      float r = sigf(g0.z + b0.z), z = sigf(g1.z + b1.z);
      o.z = (1.0f - z) * tanhf(g2.z + r * b2.z);
    }
    {
      float r = sigf(g0.w + b0.w), z = sigf(g1.w + b1.w);
      o.w = (1.0f - z) * tanhf(g2.w + r * b2.w);
    }
    ((float4*)(cat + HH))[tid] = o;
    ((float4*)(xcat + DD))[tid] = o;
  }
  __syncthreads();
  float s = 0.f;
  for (int i = tid; i < DD; i += 1024) s += halt_w[HH + i] * cat[HH + i];
  s = wred(s);
  if (lane == 0) red[wib] = s;
  __syncthreads();
  if (tid == 0) {
    float hl = 0.f;
#pragma unroll
    for (int k = 0; k < 16; k++) hl += red[k];
    float raw = sigf(scal[8] + conv_b[0]);
    scal[6] = raw;
    scal[3] = 0.1f * raw;                 // mom = 0.9*0 + 0.1*raw
    float halt = sigf(scal[9] + hl + halt_b[0]);
    float p = fminf(halt, 1.0f);          // cum was 0
    scal[10] = p;                         // p0
    scal[11] = 0.0f;                      // p1 default
    scal[1] = p;                          // weight
    scal[0] = p;                          // cum
    scal[4] = (p > 0.95f) ? 0.0f : 1.0f;  // active
    scal[5] = 0.0f;
  }
}

// ---- D2: task pool {gh_l (6144 rows) || res0 (2048 rows)} — both read l0 only
__global__ __launch_bounds__(256) void kDE_pool(
    const float* __restrict__ l_whh, const float* __restrict__ l_bhh,
    const float* __restrict__ out_w, const float* __restrict__ out_b,
    const float* __restrict__ cat, float* __restrict__ gh_l,
    float* __restrict__ res) {
  int t = (int)((blockIdx.x * 256 + threadIdx.x) >> 6);
  if (t >= 8192) return;
  int lane = threadIdx.x & 63;
  const float4* l04 = (const float4*)(cat + HH);
  if (t < 6144) {
    float s = dot8((const float4*)l_whh + (size_t)t * 512, l04, 512, lane);
    if (lane == 0) gh_l[t] = s + l_bhh[t];
  } else {
    int r = t - 6144;
    float s = dot8((const float4*)out_w + (size_t)r * 512, l04, 512, lane);
    if (lane == 0) res[r] = tanhf(s + out_b[r]);
  }
}

// ---- E1: step-1 l-combine (gi_l reused: dir unchanged), float4; + halt-l + p1
__global__ __launch_bounds__(1024) void s1_B(
    const float* __restrict__ gi_l, const float* __restrict__ gh_l,
    float* __restrict__ cat, float* __restrict__ xcat,
    const float* __restrict__ halt_b, const float* __restrict__ halt_w,
    float* __restrict__ scal) {
  __shared__ float red[16];
  int tid = threadIdx.x, lane = tid & 63, wib = tid >> 6;
  if (scal[4] == 0.0f) return;            // p1 stays 0 from s0_B
  if (tid < DD / 4) {
    const float4* g4 = (const float4*)gi_l;
    const float4* h4 = (const float4*)gh_l;
    float4 g0 = g4[tid], g1 = g4[DD / 4 + tid], g2 = g4[DD / 2 + tid];
    float4 q0 = h4[tid], q1 = h4[DD / 4 + tid], q2 = h4[DD / 2 + tid];
    float4 lp = ((const float4*)(cat + HH))[tid];
    float4 o;
    {
      float r = sigf(g0.x + q0.x), z = sigf(g1.x + q1.x);
      o.x = (1.0f - z) * tanhf(g2.x + r * q2.x) + z * lp.x;
    }
    {
      float r = sigf(g0.y + q0.y), z = sigf(g1.y + q1.y);
      o.y = (1.0f - z) * tanhf(g2.y + r * q2.y) + z * lp.y;
    }
    {
      float r = sigf(g0.z + q0.z), z = sigf(g1.z + q1.z);
      o.z = (1.0f - z) * tanhf(g2.z + r * q2.z) + z * lp.z;
    }
    {
      float r = sigf(g0.w + q0.w), z = sigf(g1.w + q1.w);
      o.w = (1.0f - z) * tanhf(g2.w + r * q2.w) + z * lp.w;
    }
    ((float4*)(cat + HH))[tid] = o;
    ((float4*)(xcat + DD))[tid] = o;
  }
  __syncthreads();
  float s = 0.f;
  for (int i = tid; i < DD; i += 1024) s += halt_w[HH + i] * cat[HH + i];
  s = wred(s);
  if (lane == 0) red[wib] = s;
  __syncthreads();
  if (tid == 0) {
    float hl = 0.f;
#pragma unroll
    for (int k = 0; k < 16; k++) hl += red[k];
    scal[3] = 0.9f * scal[3] + 0.1f * scal[6];   // raw unchanged (h unchanged)
    float halt = sigf(scal[9] + hl + halt_b[0]);
    float cum = scal[0];
    float p = fminf(halt, 1.0f - cum);
    scal[11] = p;                                 // p1
    scal[1] += p;
    cum += p;
    scal[0] = cum;
    scal[4] = (cum > 0.95f) ? 0.0f : 1.0f;
  }
}

// ---- F: fused res1 + output on fast path; rare path = generic steps 2..15
__global__ __launch_bounds__(256, 2) void kF_rest(
    const float* __restrict__ h_wih, const float* __restrict__ h_whh,
    const float* __restrict__ h_bih, const float* __restrict__ h_bhh,
    const float* __restrict__ l_wih, const float* __restrict__ l_whh,
    const float* __restrict__ l_bih, const float* __restrict__ l_bhh,
    const float* __restrict__ dir_w, const float* __restrict__ dir_b,
    const float* __restrict__ conv_w, const float* __restrict__ conv_b,
    const float* __restrict__ out_w, const float* __restrict__ out_b,
    const float* __restrict__ halt_w, const float* __restrict__ halt_b,
    const float* __restrict__ reset_w, const float* __restrict__ reset_b,
    const float* __restrict__ init_w, const float* __restrict__ init_b,
    float* __restrict__ ws, float* __restrict__ out, unsigned nblk) {
  const int tid = threadIdx.x, lane = tid & 63, wib = tid >> 6;
  const int nw = (int)(gridDim.x << 2);
  const int wid = (int)((blockIdx.x << 2) | wib);
  const int gtid = (int)(blockIdx.x * 256 + tid);
  const int gsz = (int)(gridDim.x * 256);
  float* cat = ws + OFF_CAT;
  float* gi_h = ws + OFF_GI_H;
  float* gh_h = ws + OFF_GH_H;
  float* gi_l = ws + OFF_GI_L;
  float* gh_l = ws + OFF_GH_L;
  float* dir = ws + OFF_DIR;
  float* res = ws + OFF_RES;
  float* result = ws + OFF_RESULT;
  float* scal = ws + OFF_SCAL;
  float* xcat = ws + OFF_XCAT;
  unsigned* bar = (unsigned*)(ws + OFF_BAR);
  volatile float* vs = scal;
  unsigned lg = 0;

  const float4* l14 = (const float4*)(cat + HH);    // l1 (or l0 if step-1 skipped)
  float p0v = vs[10], p1v = vs[11];

  if (vs[4] == 0.0f) {                       // common case: halted after <=2 steps
    float wgt = fmaxf(vs[1], 1e-8f);
    if (p1v == 0.0f) {                       // halted at step 0
      for (int i = gtid; i < DD; i += gsz) out[i] = p0v * res[i] / wgt;
    } else {                                 // compute res1 row per wave, write out
      for (int w = wid; w < DD; w += nw) {
        float s = dot8((const float4*)out_w + (size_t)w * 512, l14, 512, lane);
        if (lane == 0)
          out[w] = (p0v * res[w] + p1v * tanhf(s + out_b[w])) / wgt;
      }
    }
    return;
  }

  // rare path: seed result with p0*res0 + p1*res1 (res1 computed inline)
  if (p1v == 0.0f) {
    for (int i = gtid; i < DD; i += gsz) result[i] = p0v * res[i];
  } else {
    for (int w = wid; w < DD; w += nw) {
      float s = dot8((const float4*)out_w + (size_t)w * 512, l14, 512, lane);
      if (lane == 0)
        result[w] = p0v * res[w] + p1v * tanhf(s + out_b[w]);
    }
  }
  GBAR;
  for (int step = 2; step < NSTEPS; ++step) {
    if (vs[4] == 0.0f) break;
    const bool hstep = ((step & 3) == 0);
    if (hstep) {
      for (int r = wid; r < 6 * HH; r += nw) {
        if (r < 3 * HH) {
          float s = dot8((const float4*)h_wih + (size_t)r * 1024,
                         (const float4*)xcat, 1024, lane);
          if (lane == 0) gi_h[r] = s + h_bih[r];
        } else {
          int rr = r - 3 * HH;
          float s = dot8((const float4*)h_whh + (size_t)rr * 1024,
                         (const float4*)cat, 1024, lane);
          if (lane == 0) gh_h[rr] = s + h_bhh[rr];
        }
      }
      GBAR;
      for (int i = gtid; i < HH; i += gsz) {
        float rr = sigf(gi_h[i] + gh_h[i]);
        float z = sigf(gi_h[HH + i] + gh_h[HH + i]);
        float nn = tanhf(gi_h[2 * HH + i] + rr * gh_h[2 * HH + i]);
        cat[i] = (1.0f - z) * nn + z * cat[i];
      }
      GBAR;
      for (int r = wid; r < DD; r += nw) {
        float s = dot8((const float4*)dir_w + (size_t)r * 1024,
                       (const float4*)cat, 1024, lane);
        if (lane == 0) dir[r] = tanhf(s + dir_b[r]);
      }
      GBAR;
    }
    {
      const int tot = hstep ? 12288 : 6144;   // gi_l only when dir changed
      for (int r = wid; r < tot; r += nw) {
        if (r < 6144) {
          float s = dot8((const float4*)l_whh + (size_t)r * 512,
                         (const float4*)(cat + HH), 512, lane);
          if (lane == 0) gh_l[r] = s + l_bhh[r];
        } else {
          int rr = r - 6144;
          float s = dot8((const float4*)l_wih + (size_t)rr * 512,
                         (const float4*)dir, 512, lane);
          if (lane == 0) gi_l[rr] = s + l_bih[rr];
        }
      }
    }
    GBAR;
    for (int i = gtid; i < DD; i += gsz) {
      float rr = sigf(gi_l[i] + gh_l[i]);
      float z = sigf(gi_l[DD + i] + gh_l[DD + i]);
      float nn = tanhf(gi_l[2 * DD + i] + rr * gh_l[2 * DD + i]);
      float lv = (1.0f - z) * nn + z * cat[HH + i];
      cat[HH + i] = lv;
      xcat[DD + i] = lv;
    }
    GBAR;
    for (int r = wid; r < DD; r += nw) {
      float s = dot8((const float4*)out_w + (size_t)r * 512,
                     (const float4*)(cat + HH), 512, lane);
      if (lane == 0) res[r] = tanhf(s + out_b[r]);
    }
    GBAR;
    if (blockIdx.x == 0) {
      __shared__ float red[4];
      __shared__ float s_p;
      float s = 0.f;
      if (wib == 0) {
        if (hstep) {
          for (int i = lane; i < HH; i += 64) s += conv_w[i] * cat[i];
          s = wred(s);
          if (lane == 0) red[0] = s;
        }
      } else if (wib == 1) {
        for (int i = lane; i < HH + DD; i += 64) s += halt_w[i] * cat[i];
        s = wred(s);
        if (lane == 0) red[1] = s;
      } else if (wib == 2) {
        for (int i = lane; i < HH + DD; i += 64) s += reset_w[i] * cat[i];
        s = wred(s);
        if (lane == 0) red[2] = s;
      }
      __syncthreads();
      if (tid == 0) {
        float raw = hstep ? sigf(red[0] + conv_b[0]) : scal[6];
        if (hstep) scal[6] = raw;
        float mom = 0.9f * scal[3] + 0.1f * raw;
        scal[3] = mom;
        float halt = sigf(red[1] + halt_b[0]);
        float cum = scal[0];
        float p = fminf(halt, 1.0f - cum);
        scal[1] += p;
        cum += p;
        scal[0] = cum;
        bool brk = cum > 0.95f;
        float rdot = red[2] + reset_w[HH + DD] * mom + reset_b[0];
        scal[5] = (!brk && (sigf(rdot) > 0.7f) && (step > KK)) ? 1.0f : 0.0f;
        scal[4] = brk ? 0.0f : 1.0f;
        s_p = p;
      }
      __syncthreads();
      float p = s_p;
      for (int i = tid; i < DD; i += 256) result[i] += p * res[i];
      __threadfence();
    }
    GBAR;
    if (step > KK && vs[5] != 0.0f) {
      for (int r = wid; r < DD; r += nw) {
        float s = dot8((const float4*)init_w + (size_t)r * 1024,
                       (const float4*)cat, 1024, lane);
        if (lane == 0) {
          float lv = tanhf(s + init_b[r]);
          cat[HH + r] = lv;
          xcat[DD + r] = lv;
        }
      }
      GBAR;
    }
  }
  float wgt = fmaxf(vs[1], 1e-8f);
  for (int i = gtid; i < DD; i += gsz) out[i] = result[i] / wgt;
}

extern "C" void kernel_launch(void* const* d_in, const int* in_sizes, int n_in,
                              void* d_out, int out_size, void* d_ws, size_t ws_size,
                              hipStream_t stream) {
  const float* query   = (const float*)d_in[0];
  const float* h_wih   = (const float*)d_in[1];
  const float* h_whh   = (const float*)d_in[2];
  const float* h_bih   = (const float*)d_in[3];
  const float* h_bhh   = (const float*)d_in[4];
  const float* l_wih   = (const float*)d_in[5];
  const float* l_whh   = (const float*)d_in[6];
  const float* l_bih   = (const float*)d_in[7];
  const float* l_bhh   = (const float*)d_in[8];
  const float* dir_w   = (const float*)d_in[9];
  const float* dir_b   = (const float*)d_in[10];
  const float* conv_w  = (const float*)d_in[11];
  const float* conv_b  = (const float*)d_in[12];
  const float* out_w   = (const float*)d_in[13];
  const float* out_b   = (const float*)d_in[14];
  const float* halt_w  = (const float*)d_in[15];
  const float* halt_b  = (const float*)d_in[16];
  const float* reset_w = (const float*)d_in[17];
  const float* reset_b = (const float*)d_in[18];
  const float* init_w  = (const float*)d_in[19];
  const float* init_b  = (const float*)d_in[20];

  float* ws = (float*)d_ws;
  float* out = (float*)d_out;
  float* cat  = ws + OFF_CAT;
  float* gi_h = ws + OFF_GI_H;
  float* gi_l = ws + OFF_GI_L;
  float* gh_l = ws + OFF_GH_L;
  float* dir  = ws + OFF_DIR;
  float* res  = ws + OFF_RES;
  float* scal = ws + OFF_SCAL;
  float* xcat = ws + OFF_XCAT;
  unsigned* bar = (unsigned*)(ws + OFF_BAR);

  // step 0 specialization (h=0, l=0)
  kA_gih<<<3072, 256, 0, stream>>>(h_wih, h_bih, query, gi_h, xcat);
  s0_hcombine<<<4, 256, 0, stream>>>(gi_h, h_bhh, cat, bar);
  k_dir_conv<<<513, 256, 0, stream>>>(dir_w, dir_b, conv_w, halt_w, cat, dir, scal);
  kC_gil<<<1536, 256, 0, stream>>>(l_wih, l_bih, dir, gi_l);
  s0_B<<<1, 1024, 0, stream>>>(gi_l, l_bhh, cat, xcat, conv_b, halt_w, halt_b, scal);
  // {gh_l || res0} task pool (both depend only on l0)
  kDE_pool<<<2048, 256, 0, stream>>>(l_whh, l_bhh, out_w, out_b, cat, gh_l, res);
  // step 1 (h, dir, gi_l unchanged)
  s1_B<<<1, 1024, 0, stream>>>(gi_l, gh_l, cat, xcat, halt_b, halt_w, scal);
  // output (with fused res1) / rare remainder
  int maxb = 0;
  if (hipOccupancyMaxActiveBlocksPerMultiprocessor(&maxb, kF_rest, 256, 0) != hipSuccess)
    maxb = 1;
  unsigned nblk = (maxb >= 2) ? 512u : 256u;
  kF_rest<<<nblk, 256, 0, stream>>>(h_wih, h_whh, h_bih, h_bhh,
                                    l_wih, l_whh, l_bih, l_bhh,
                                    dir_w, dir_b, conv_w, conv_b,
                                    out_w, out_b, halt_w, halt_b,
                                    reset_w, reset_b, init_w, init_b,
                                    ws, out, nblk);
}